// Round 2
// baseline (326.496 us; speedup 1.0000x reference)
//
#include <hip/hip_runtime.h>

// IF spiking neuron, T=8, (B=32, CHW=200704) fp32 streaming, zero reuse.
// 205 MB in + 205 MB out = 411 MB; mixed-stream roofline @ ~6.45 TB/s
// (measured from harness's own 784 MiB poison fills) = ~64 us.
//
// R1 finding: our kernel dispatch is ABSENT from rocprof top-5 (all five are
// 127-us harness poison fills) => kernel <= 126 us; harness dur_us=318.5
// includes >= 193 us of fills. Decomposition 318.5 - 2x127.3 = 63.9 us
// matches the roofline exactly (H-A), but 1-fill decomposition (kernel
// ~160-191 us) can't be excluded from counters alone.
//
// R2 probe = structurally different BW-saturating design (ceiling
// cross-check, methodology rule 10):
//   - 1568 blocks x 256 thr = 6272 waves: ENTIRE grid resident at once
//     (cap 8192/chip) -> single generation, no ramp/drain boundaries.
//   - 4 chains per thread (b, b+8, b+16, b+24), 4x8 full unroll -> up to
//     32 independent nt loads in flight per thread.
//   - Same nt/nt policy (measured-best quadrant), same dwordx4 coalescing.
// Prediction: H-A -> dur_us 318+-4 (declare roofline next round);
//             H-B -> -10..40 us.

typedef float v4f __attribute__((ext_vector_type(4)));

#define CHW_VEC 50176   // 64*56*56 / 4
#define TSTEPS 8
#define NBATCH 32
#define BLK 256
#define BCHAINS 4       // batches per thread
#define GRID_Y (NBATCH / BCHAINS)   // 8

__global__ __launch_bounds__(BLK) void IF_33122787787165_kernel(
    const v4f* __restrict__ x, v4f* __restrict__ out) {
    const unsigned i = blockIdx.x * BLK + threadIdx.x;   // vec4 idx in CHW

#pragma unroll
    for (int bb = 0; bb < BCHAINS; ++bb) {
        const unsigned b = blockIdx.y + (unsigned)(GRID_Y * bb);
        const unsigned base = b * (TSTEPS * CHW_VEC) + i;

        v4f mem = (v4f)(0.0f);
#pragma unroll
        for (int t = 0; t < TSTEPS; ++t) {
            const v4f xt =
                __builtin_nontemporal_load(&x[base + (unsigned)t * CHW_VEC]);
            v4f m = mem + xt;
            v4f s;
            s.x = (m.x > 1.0f) ? 1.0f : 0.0f;
            s.y = (m.y > 1.0f) ? 1.0f : 0.0f;
            s.z = (m.z > 1.0f) ? 1.0f : 0.0f;
            s.w = (m.w > 1.0f) ? 1.0f : 0.0f;
            m.x = (m.x > 1.0f) ? 0.0f : m.x;
            m.y = (m.y > 1.0f) ? 0.0f : m.y;
            m.z = (m.z > 1.0f) ? 0.0f : m.z;
            m.w = (m.w > 1.0f) ? 0.0f : m.w;
            mem = m;
            __builtin_nontemporal_store(s, &out[base + (unsigned)t * CHW_VEC]);
        }
    }
}

extern "C" void kernel_launch(void* const* d_in, const int* in_sizes, int n_in,
                              void* d_out, int out_size, void* d_ws, size_t ws_size,
                              hipStream_t stream) {
    const v4f* x = (const v4f*)d_in[0];
    v4f* out = (v4f*)d_out;
    dim3 grid(CHW_VEC / BLK, GRID_Y);  // 196 x 8 = 1568 blocks, 6272 waves
    IF_33122787787165_kernel<<<grid, BLK, 0, stream>>>(x, out);
}

// Round 3
// 319.795 us; speedup vs baseline: 1.0210x; 1.0210x over previous
//
#include <hip/hip_runtime.h>

// IF spiking neuron, T=8 over (B=32, T=8, CHW=200704) fp32. Streaming,
// zero-reuse: 205.5 MB in + 205.5 MB out = 411 MB mandatory traffic.
//
// FINAL — at the HBM mixed-stream roofline. Evidence chain:
//  R1: kernel dispatch absent from rocprof top-5 (all five = 127-us harness
//      poison fills @ 6.45-6.54 TB/s) => kernel <= 126 us; harness
//      dur_us=318.5 includes ~254 us of fills.
//  R2: structurally different design (1568 blocks, 4 chains/thread, fully
//      resident grid) = 326.5 us => restructures neutral-to-worse, matching
//      prior session's sweep (VPT=2, burst-load, cache-policy 2x2: 320-344).
//  Decomposition: only the 2-fill split is consistent with top-5 absence:
//      kernel = 318.5 - 2x127.3 = ~64 us = 411 MB / 6.4 TB/s — equal to the
//      achievable mixed-stream BW cross-calibrated from the harness's own
//      fills (6.45-6.63 TB/s) in the same replay. No headroom remains:
//      traffic is mandatory (fp32 out required by ref), access is fully
//      coalesced dwordx4, occupancy-unconstrained (8 VGPR-class kernel),
//      nt/nt was the measured-best cache-policy quadrant.
//
// Config: VPT=1 interleaved, 6272 blocks (196x32), 256 thr, nt load + nt
// store both directions.

typedef float v4f __attribute__((ext_vector_type(4)));

#define CHW_VEC 50176   // 64*56*56 / 4
#define TSTEPS 8
#define NBATCH 32
#define BLK 256

__global__ __launch_bounds__(BLK) void IF_33122787787165_kernel(
    const v4f* __restrict__ x, v4f* __restrict__ out) {
    const unsigned i = blockIdx.x * BLK + threadIdx.x;   // vec4 idx in CHW
    const unsigned b = blockIdx.y;
    const unsigned base = b * (TSTEPS * CHW_VEC) + i;

    v4f mem = (v4f)(0.0f);
#pragma unroll
    for (int t = 0; t < TSTEPS; ++t) {
        const v4f xt = __builtin_nontemporal_load(&x[base + (unsigned)t * CHW_VEC]);
        v4f m = mem + xt;
        v4f s;
        s.x = (m.x > 1.0f) ? 1.0f : 0.0f;
        s.y = (m.y > 1.0f) ? 1.0f : 0.0f;
        s.z = (m.z > 1.0f) ? 1.0f : 0.0f;
        s.w = (m.w > 1.0f) ? 1.0f : 0.0f;
        m.x = (m.x > 1.0f) ? 0.0f : m.x;
        m.y = (m.y > 1.0f) ? 0.0f : m.y;
        m.z = (m.z > 1.0f) ? 0.0f : m.z;
        m.w = (m.w > 1.0f) ? 0.0f : m.w;
        mem = m;
        __builtin_nontemporal_store(s, &out[base + (unsigned)t * CHW_VEC]);
    }
}

extern "C" void kernel_launch(void* const* d_in, const int* in_sizes, int n_in,
                              void* d_out, int out_size, void* d_ws, size_t ws_size,
                              hipStream_t stream) {
    const v4f* x = (const v4f*)d_in[0];
    v4f* out = (v4f*)d_out;
    dim3 grid(CHW_VEC / BLK, NBATCH);  // 196 x 32 blocks
    IF_33122787787165_kernel<<<grid, BLK, 0, stream>>>(x, out);
}